// Round 4
// baseline (529.276 us; speedup 1.0000x reference)
//
#include <hip/hip_runtime.h>
#include <hip/hip_bf16.h>

#define DIM   1536
#define HEADS 12
#define HD    128
#define SEQ   4096
#define QSCALE 0.08838834764831845f
#define LOG2E 1.44269504088896f

typedef __attribute__((ext_vector_type(8))) short short8;
typedef __attribute__((ext_vector_type(4))) float f32x4;

__device__ __forceinline__ unsigned short f2bf(float f) {
    __hip_bfloat16 h = __float2bfloat16(f);
    return *reinterpret_cast<unsigned short*>(&h);
}
__device__ __forceinline__ float bf2f(unsigned short u) {
    return __uint_as_float(((unsigned int)u) << 16);
}

// ---------------------------------------------------------------------------
// GEMM: y = x @ W^T + b, fused QKV via blockIdx.z. M=4096, N=1536, K=1536.
// 128x128 tile, BK=32, 4 waves each 64x64 (4x4 frags of 16x16x32 bf16 MFMA).
// f32 inputs converted to bf16 during LDS staging. All outputs bf16.
// ---------------------------------------------------------------------------
__global__ __launch_bounds__(256) void gemm_qkv(
    const float* __restrict__ x,
    const float* __restrict__ wq, const float* __restrict__ bq,
    const float* __restrict__ wk, const float* __restrict__ bk,
    const float* __restrict__ wv, const float* __restrict__ bv,
    __hip_bfloat16* __restrict__ yq, __hip_bfloat16* __restrict__ yk,
    __hip_bfloat16* __restrict__ vrow)
{
    __shared__ __align__(16) short As[128][40];
    __shared__ __align__(16) short Bs[128][40];
    const int z  = blockIdx.z;
    const float* W    = (z == 0) ? wq : (z == 1) ? wk : wv;
    const float* bias = (z == 0) ? bq : (z == 1) ? bk : bv;
    __hip_bfloat16* outp = (z == 0) ? yq : (z == 1) ? yk : vrow;
    const int bm0 = blockIdx.x * 128;
    const int bn0 = blockIdx.y * 128;
    const int tid  = threadIdx.x;
    const int lane = tid & 63;
    const int wid  = tid >> 6;
    const int wm = (wid >> 1) * 64;
    const int wn = (wid & 1)  * 64;
    const int fr = lane & 15;
    const int fc = (lane >> 4) * 8;
    const int srow = tid >> 3;          // 0..31
    const int scol = (tid & 7) * 4;     // 0,4,...,28

    f32x4 acc[4][4] = {};

    for (int kt = 0; kt < DIM; kt += 32) {
        #pragma unroll
        for (int p = 0; p < 4; ++p) {
            const int r = srow + p * 32;
            float4 va = *reinterpret_cast<const float4*>(&x[(size_t)(bm0 + r) * DIM + kt + scol]);
            float4 vb = *reinterpret_cast<const float4*>(&W[(size_t)(bn0 + r) * DIM + kt + scol]);
            uint2 pa, pb;
            pa.x = (unsigned int)f2bf(va.x) | ((unsigned int)f2bf(va.y) << 16);
            pa.y = (unsigned int)f2bf(va.z) | ((unsigned int)f2bf(va.w) << 16);
            pb.x = (unsigned int)f2bf(vb.x) | ((unsigned int)f2bf(vb.y) << 16);
            pb.y = (unsigned int)f2bf(vb.z) | ((unsigned int)f2bf(vb.w) << 16);
            *reinterpret_cast<uint2*>(&As[r][scol]) = pa;
            *reinterpret_cast<uint2*>(&Bs[r][scol]) = pb;
        }
        __syncthreads();
        short8 af[4], bf8[4];
        #pragma unroll
        for (int m = 0; m < 4; m++) af[m]  = *reinterpret_cast<const short8*>(&As[wm + m * 16 + fr][fc]);
        #pragma unroll
        for (int n = 0; n < 4; n++) bf8[n] = *reinterpret_cast<const short8*>(&Bs[wn + n * 16 + fr][fc]);
        #pragma unroll
        for (int m = 0; m < 4; m++)
            #pragma unroll
            for (int n = 0; n < 4; n++)
                acc[m][n] = __builtin_amdgcn_mfma_f32_16x16x32_bf16(af[m], bf8[n], acc[m][n], 0, 0, 0);
        __syncthreads();
    }

    const int crow0 = bm0 + wm + (lane >> 4) * 4;
    const int ccol0 = bn0 + wn + fr;
    #pragma unroll
    for (int n = 0; n < 4; n++) {
        const int col = ccol0 + n * 16;
        const float bb = bias[col];
        #pragma unroll
        for (int m = 0; m < 4; m++)
            #pragma unroll
            for (int r = 0; r < 4; r++)
                outp[(size_t)(crow0 + m * 16 + r) * DIM + col] =
                    __float2bfloat16(acc[m][n][r] + bb);
    }
}

// ---------------------------------------------------------------------------
// In-place RMSNorm (over full DIM) * g + RoPE, on bf16 rows.
// z==0: q (also scaled by 1/sqrt(HD)), z==1: k. One block per position.
// ---------------------------------------------------------------------------
__global__ __launch_bounds__(256) void rmsnorm_rope(
    __hip_bfloat16* __restrict__ yq, __hip_bfloat16* __restrict__ yk,
    const float* __restrict__ gq, const float* __restrict__ gk,
    const float* __restrict__ freqs)
{
    const int s = blockIdx.x;
    const int z = blockIdx.y;
    __hip_bfloat16* y = z ? yk : yq;
    const float* g = z ? gk : gq;
    const int t = threadIdx.x;

    float xr[3], xi[3];
    float ss = 0.f;
    #pragma unroll
    for (int i = 0; i < 3; i++) {
        const int p = t + i * 256;
        const unsigned int uu = *reinterpret_cast<const unsigned int*>(&y[(size_t)s * DIM + 2 * p]);
        xr[i] = bf2f((unsigned short)(uu & 0xffffu));
        xi[i] = bf2f((unsigned short)(uu >> 16));
        ss += xr[i] * xr[i] + xi[i] * xi[i];
    }
    #pragma unroll
    for (int m = 1; m < 64; m <<= 1) ss += __shfl_xor(ss, m, 64);
    __shared__ float red[4];
    if ((t & 63) == 0) red[t >> 6] = ss;
    __syncthreads();
    const float sum = red[0] + red[1] + red[2] + red[3];
    const float rs = rsqrtf(sum * (1.0f / DIM) + 1e-6f);
    const int f = s >> 8, hh = (s >> 4) & 15, ww = s & 15;
    const float osc = z ? 1.0f : QSCALE;
    #pragma unroll
    for (int i = 0; i < 3; i++) {
        const int p = t + i * 256;
        const int cc = p & 63;
        const int pos = (cc < 22) ? f : (cc < 43) ? hh : ww;
        const float ang = freqs[pos * 64 + cc];
        float sn, cs;
        sincosf(ang, &sn, &cs);
        const float a = xr[i] * rs * g[2 * p];
        const float b = xi[i] * rs * g[2 * p + 1];
        const unsigned int pk = (unsigned int)f2bf((a * cs - b * sn) * osc)
                              | ((unsigned int)f2bf((a * sn + b * cs) * osc) << 16);
        *reinterpret_cast<unsigned int*>(&y[(size_t)s * DIM + 2 * p]) = pk;
    }
}

// ---------------------------------------------------------------------------
// Transpose V: vrow [4096][1536] bf16 -> vT [1536][4096] bf16 ([12][128][4096])
// ---------------------------------------------------------------------------
__global__ __launch_bounds__(256) void transpose_v(
    const __hip_bfloat16* __restrict__ vrow,
    __hip_bfloat16* __restrict__ vT)
{
    __shared__ __align__(16) short tile[64][72];
    const int s0 = blockIdx.x * 64;
    const int c0 = blockIdx.y * 64;
    const int t = threadIdx.x;
    #pragma unroll
    for (int i = 0; i < 2; i++) {
        const int ch = t + i * 256;
        const int r = ch >> 3, cc = (ch & 7) * 8;
        *reinterpret_cast<int4*>(&tile[r][cc]) =
            *reinterpret_cast<const int4*>(&vrow[(size_t)(s0 + r) * DIM + c0 + cc]);
    }
    __syncthreads();
    #pragma unroll
    for (int i = 0; i < 2; i++) {
        const int ch = t + i * 256;
        const int c = ch & 63, sc = (ch >> 6) * 8;
        unsigned int w0 = (unsigned short)tile[sc + 0][c] | ((unsigned int)(unsigned short)tile[sc + 1][c] << 16);
        unsigned int w1 = (unsigned short)tile[sc + 2][c] | ((unsigned int)(unsigned short)tile[sc + 3][c] << 16);
        unsigned int w2 = (unsigned short)tile[sc + 4][c] | ((unsigned int)(unsigned short)tile[sc + 5][c] << 16);
        unsigned int w3 = (unsigned short)tile[sc + 6][c] | ((unsigned int)(unsigned short)tile[sc + 7][c] << 16);
        int4 val;
        val.x = (int)w0; val.y = (int)w1; val.z = (int)w2; val.w = (int)w3;
        *reinterpret_cast<int4*>(&vT[(size_t)(c0 + c) * SEQ + s0 + sc]) = val;
    }
}

// ---------------------------------------------------------------------------
// Flash attention, full MFMA. Block = (64 q-rows, head). 4 waves x 16 q-rows.
// Online softmax; q pre-scaled by 1/sqrt(HD). V consumed via vT (B-fragments).
// ---------------------------------------------------------------------------
__global__ __launch_bounds__(256) void flash_attn(
    const __hip_bfloat16* __restrict__ qb,
    const __hip_bfloat16* __restrict__ kb,
    const __hip_bfloat16* __restrict__ vT,
    const int* __restrict__ seq_lens,
    __hip_bfloat16* __restrict__ attno)
{
    __shared__ __align__(16) short Ks[64][136];
    __shared__ __align__(16) short Vs[128][72];
    __shared__ __align__(16) short Ps[4][16][72];
    const int qt = blockIdx.x;
    const int h  = blockIdx.y;
    const int tid = threadIdx.x;
    const int lane = tid & 63;
    const int w = tid >> 6;
    const int fr = lane & 15;
    const int fg = lane >> 4;       // 0..3
    const int seqlen = seq_lens[0];

    short8 qf[4];
    const int qrow = qt * 64 + w * 16 + fr;
    #pragma unroll
    for (int kc = 0; kc < 4; kc++)
        qf[kc] = *reinterpret_cast<const short8*>(&qb[(size_t)qrow * DIM + h * HD + kc * 32 + fg * 8]);

    f32x4 oacc[8] = {};
    float mrow[4], lrow[4];
    #pragma unroll
    for (int r = 0; r < 4; r++) { mrow[r] = -1e30f; lrow[r] = 0.f; }

    for (int kbase = 0; kbase < SEQ; kbase += 64) {
        // stage K tile: 64 rows x 128 cols
        #pragma unroll
        for (int i = 0; i < 4; i++) {
            const int ch = tid + i * 256;
            const int r = ch >> 4, cc = (ch & 15) * 8;
            *reinterpret_cast<int4*>(&Ks[r][cc]) =
                *reinterpret_cast<const int4*>(&kb[(size_t)(kbase + r) * DIM + h * HD + cc]);
        }
        // stage V^T tile: 128 channel-rows x 64 keys
        #pragma unroll
        for (int i = 0; i < 4; i++) {
            const int ch = tid + i * 256;
            const int r = ch >> 3, cc = (ch & 7) * 8;
            *reinterpret_cast<int4*>(&Vs[r][cc]) =
                *reinterpret_cast<const int4*>(&vT[((size_t)h * HD + r) * SEQ + kbase + cc]);
        }
        __syncthreads();

        // S = Q K^T  (16 rows x 64 keys per wave)
        f32x4 sacc[4] = {};
        #pragma unroll
        for (int kc = 0; kc < 4; kc++) {
            #pragma unroll
            for (int n = 0; n < 4; n++) {
                short8 kf = *reinterpret_cast<const short8*>(&Ks[n * 16 + fr][kc * 32 + fg * 8]);
                sacc[n] = __builtin_amdgcn_mfma_f32_16x16x32_bf16(qf[kc], kf, sacc[n], 0, 0, 0);
            }
        }
        // mask + row max (rows = fg*4 + r, keys spread over 16-lane group)
        float pm[4] = {-1e30f, -1e30f, -1e30f, -1e30f};
        #pragma unroll
        for (int n = 0; n < 4; n++) {
            const int key = kbase + n * 16 + fr;
            const bool valid = key < seqlen;
            #pragma unroll
            for (int r = 0; r < 4; r++) {
                const float sv = valid ? sacc[n][r] : -1e30f;
                sacc[n][r] = sv;
                pm[r] = fmaxf(pm[r], sv);
            }
        }
        #pragma unroll
        for (int m = 1; m < 16; m <<= 1) {
            #pragma unroll
            for (int r = 0; r < 4; r++) pm[r] = fmaxf(pm[r], __shfl_xor(pm[r], m, 16));
        }
        float alpha[4];
        #pragma unroll
        for (int r = 0; r < 4; r++) {
            const float mnew = fmaxf(mrow[r], pm[r]);
            alpha[r] = exp2f((mrow[r] - mnew) * LOG2E);
            mrow[r] = mnew;
        }
        // P = exp(S - m): row sums + stash bf16 P in per-wave LDS
        float psum[4] = {0.f, 0.f, 0.f, 0.f};
        #pragma unroll
        for (int n = 0; n < 4; n++) {
            #pragma unroll
            for (int r = 0; r < 4; r++) {
                const float p = exp2f((sacc[n][r] - mrow[r]) * LOG2E);
                psum[r] += p;
                Ps[w][fg * 4 + r][n * 16 + fr] = (short)f2bf(p);
            }
        }
        #pragma unroll
        for (int m = 1; m < 16; m <<= 1) {
            #pragma unroll
            for (int r = 0; r < 4; r++) psum[r] += __shfl_xor(psum[r], m, 16);
        }
        #pragma unroll
        for (int r = 0; r < 4; r++) lrow[r] = lrow[r] * alpha[r] + psum[r];
        #pragma unroll
        for (int n = 0; n < 8; n++)
            #pragma unroll
            for (int r = 0; r < 4; r++) oacc[n][r] *= alpha[r];
        __syncthreads();

        // O += P V   (P: 16x64 A-frags from LDS; V^T rows as B-frags)
        #pragma unroll
        for (int kc = 0; kc < 2; kc++) {
            const short8 pf = *reinterpret_cast<const short8*>(&Ps[w][fr][kc * 32 + fg * 8]);
            #pragma unroll
            for (int n = 0; n < 8; n++) {
                short8 vf = *reinterpret_cast<const short8*>(&Vs[n * 16 + fr][kc * 32 + fg * 8]);
                oacc[n] = __builtin_amdgcn_mfma_f32_16x16x32_bf16(pf, vf, oacc[n], 0, 0, 0);
            }
        }
        __syncthreads();
    }

    #pragma unroll
    for (int n = 0; n < 8; n++) {
        #pragma unroll
        for (int r = 0; r < 4; r++) {
            const float o = oacc[n][r] / lrow[r];
            const int row = qt * 64 + w * 16 + fg * 4 + r;
            const int col = h * HD + n * 16 + fr;
            attno[(size_t)row * DIM + col] = __float2bfloat16(o);
        }
    }
}

// ---------------------------------------------------------------------------
// Output GEMM: out = attno(bf16) @ wo^T(f32->bf16) + bo, **f32 out** (d_out).
// ---------------------------------------------------------------------------
__global__ __launch_bounds__(256) void gemm_out(
    const __hip_bfloat16* __restrict__ A,
    const float* __restrict__ W,
    const float* __restrict__ bias,
    float* __restrict__ outp)
{
    __shared__ __align__(16) short As[128][40];
    __shared__ __align__(16) short Bs[128][40];
    const int bm0 = blockIdx.x * 128;
    const int bn0 = blockIdx.y * 128;
    const int tid = threadIdx.x;
    const int lane = tid & 63;
    const int wid = tid >> 6;
    const int wm = (wid >> 1) * 64;
    const int wn = (wid & 1) * 64;
    const int fr = lane & 15;
    const int fc = (lane >> 4) * 8;
    const int srow = tid >> 3;
    const int scol = (tid & 7) * 4;

    f32x4 acc[4][4] = {};

    for (int kt = 0; kt < DIM; kt += 32) {
        #pragma unroll
        for (int i = 0; i < 2; i++) {
            const int ch = tid + i * 256;
            const int r = ch >> 2, cc = (ch & 3) * 8;
            *reinterpret_cast<int4*>(&As[r][cc]) =
                *reinterpret_cast<const int4*>(&A[(size_t)(bm0 + r) * DIM + kt + cc]);
        }
        #pragma unroll
        for (int p = 0; p < 4; p++) {
            const int r = srow + p * 32;
            float4 vb = *reinterpret_cast<const float4*>(&W[(size_t)(bn0 + r) * DIM + kt + scol]);
            uint2 pb;
            pb.x = (unsigned int)f2bf(vb.x) | ((unsigned int)f2bf(vb.y) << 16);
            pb.y = (unsigned int)f2bf(vb.z) | ((unsigned int)f2bf(vb.w) << 16);
            *reinterpret_cast<uint2*>(&Bs[r][scol]) = pb;
        }
        __syncthreads();
        short8 af[4], bf8[4];
        #pragma unroll
        for (int m = 0; m < 4; m++) af[m]  = *reinterpret_cast<const short8*>(&As[wm + m * 16 + fr][fc]);
        #pragma unroll
        for (int n = 0; n < 4; n++) bf8[n] = *reinterpret_cast<const short8*>(&Bs[wn + n * 16 + fr][fc]);
        #pragma unroll
        for (int m = 0; m < 4; m++)
            #pragma unroll
            for (int n = 0; n < 4; n++)
                acc[m][n] = __builtin_amdgcn_mfma_f32_16x16x32_bf16(af[m], bf8[n], acc[m][n], 0, 0, 0);
        __syncthreads();
    }

    const int crow0 = bm0 + wm + (lane >> 4) * 4;
    const int ccol0 = bn0 + wn + fr;
    #pragma unroll
    for (int n = 0; n < 4; n++) {
        const int col = ccol0 + n * 16;
        const float bb = bias[col];
        #pragma unroll
        for (int m = 0; m < 4; m++)
            #pragma unroll
            for (int r = 0; r < 4; r++)
                outp[(size_t)(crow0 + m * 16 + r) * DIM + col] = acc[m][n][r] + bb;
    }
}

// ---------------------------------------------------------------------------
extern "C" void kernel_launch(void* const* d_in, const int* in_sizes, int n_in,
                              void* d_out, int out_size, void* d_ws, size_t ws_size,
                              hipStream_t stream)
{
    const float* x        = (const float*)d_in[0];
    const int*   seq_lens = (const int*)d_in[1];
    // d_in[2] = grid_sizes (fixed 16,16,16 — unused)
    const float* freqs    = (const float*)d_in[3];
    const float* wq = (const float*)d_in[4];
    const float* bq = (const float*)d_in[5];
    const float* wk = (const float*)d_in[6];
    const float* bk = (const float*)d_in[7];
    const float* wv = (const float*)d_in[8];
    const float* bv = (const float*)d_in[9];
    const float* wo = (const float*)d_in[10];
    const float* bo = (const float*)d_in[11];
    const float* gq = (const float*)d_in[12];
    const float* gk = (const float*)d_in[13];
    float* out = (float*)d_out;    // reference output dtype is float32

    // workspace: 50,331,648 bytes total
    //   yq   bf16 [0,        12582912)   (normed+roped in place -> q)
    //   yk   bf16 [12582912, 25165824)   (in place -> k)
    //   vrow bf16 [25165824, 37748736)   (dead after transpose_v)
    //   vT   bf16 [37748736, 50331648)
    //   attno bf16 aliases vrow region.
    char* ws = (char*)d_ws;
    __hip_bfloat16* yq    = (__hip_bfloat16*)(ws);
    __hip_bfloat16* yk    = (__hip_bfloat16*)(ws + 12582912);
    __hip_bfloat16* vrow  = (__hip_bfloat16*)(ws + 25165824);
    __hip_bfloat16* vT    = (__hip_bfloat16*)(ws + 37748736);
    __hip_bfloat16* attno = (__hip_bfloat16*)(ws + 25165824);

    dim3 blk(256);
    gemm_qkv    <<<dim3(32, 12, 3), blk, 0, stream>>>(x, wq, bq, wk, bk, wv, bv, yq, yk, vrow);
    rmsnorm_rope<<<dim3(4096, 2),   blk, 0, stream>>>(yq, yk, gq, gk, freqs);
    transpose_v <<<dim3(64, 24),    blk, 0, stream>>>(vrow, vT);
    flash_attn  <<<dim3(64, 12),    blk, 0, stream>>>(yq, yk, vT, seq_lens, attno);
    gemm_out    <<<dim3(32, 12),    blk, 0, stream>>>(attno, wo, bo, out);
}